// Round 9
// baseline (928.598 us; speedup 1.0000x reference)
//
#include <hip/hip_runtime.h>

// EGNN fused layer, MI355X gfx950 — v10 (single-launch, commutative init).
// out[0 : 50000*64)          = h + segment_sum(node messages, dst)
// out[50000*64 : +50000*3)   = x + segment_sum(coord updates, dst)
//
// v9 post-mortem: 128-edge tiles REGRESSED (334->402) - 5th falsified
// main-kernel theory; v8's 64-edge body is the local optimum.  Ledger:
// aux (2 launches) = 82us = 20% of total.  This round eliminates aux:
//  - out initialized to ZERO (hipMemsetAsync), h/x added via atomicAdd in
//    the main kernel's prologue.  Atomic adds commute with the message
//    scatters -> NO ordering, NO grid sync, NO prep kernel.
//  - weight fold inlined per-block (one-time, v7 math = passing v4/v8 prep).
//  - f32 h gathers in stage phase via prefetched index regs (bf16 table
//    needs a sync; it was only worth -6us).  Register-cheap prefetch only.
//  - body otherwise = v8 (3 lgkm-only barriers, pi-packed hl, merged GEMM1,
//    direct atomic epilogue).  ONE memset + ONE kernel launch.

#define NN 50000
#define NE 800000
#define NDIM 64
#define HDIM 128
#define NTILES (NE / 64)      // 12500, exact
#define MSTRIDE 168           // m_input LDS row stride (ushorts): 160 + 8 pad
#define HSTRIDE 136           // hidden LDS row stride (ushorts): 128 + 8 pad
#define NH (NN * NDIM)        // 3,200,000
#define NX (NN * 3)           // 150,000
#define GRID 1024

typedef __bf16 bf16x8 __attribute__((ext_vector_type(8)));
typedef float f32x4 __attribute__((ext_vector_type(4)));
typedef unsigned short ushort8 __attribute__((ext_vector_type(8)));
typedef unsigned short ushort4v __attribute__((ext_vector_type(4)));

__device__ __forceinline__ unsigned short f2bf(float f) {
    union { __bf16 b; unsigned short u; } c;
    c.b = (__bf16)f;            // HW v_cvt (RNE)
    return c.u;
}
__device__ __forceinline__ float silu(float v) {
    return __fdividef(v, 1.0f + __expf(-v));
}
// lgkm-only barrier: all cross-thread deps flow through LDS; atomics and
// prefetch loads stay in flight across it.
__device__ __forceinline__ void bar_lds() {
    asm volatile("s_waitcnt lgkmcnt(0)" ::: "memory");
    __builtin_amdgcn_s_barrier();
}
__device__ __forceinline__ bf16x8 ld_frag(const unsigned short* p) {
    union { ushort8 u; bf16x8 v; } c;
    c.u = *(const ushort8*)p;
    return c.v;
}
__device__ __forceinline__ bf16x8 mk_frag(const unsigned short* u) {
    union { ushort8 uu; bf16x8 v; } c;
#pragma unroll
    for (int j = 0; j < 8; ++j) c.uu[j] = u[j];
    return c.v;
}

__global__ __launch_bounds__(256, 2) void egnn_all(
    const float* __restrict__ h, const float* __restrict__ x,
    const int* __restrict__ srcg, const int* __restrict__ dstg,
    const float* __restrict__ dist,
    const float* __restrict__ We1, const float* __restrict__ be1,
    const float* __restrict__ We2, const float* __restrict__ be2,
    const float* __restrict__ Wn1, const float* __restrict__ bn1,
    const float* __restrict__ Wn2, const float* __restrict__ bn2,
    const float* __restrict__ Wc1, const float* __restrict__ bc1,
    const float* __restrict__ Wc2,
    float* __restrict__ out) {

    __shared__ __align__(16) unsigned short mlds[64 * MSTRIDE];  // m_input tile bf16
    __shared__ __align__(16) unsigned short hl[64 * HSTRIDE];    // hidden tile bf16 (pi-permuted)
    __shared__ int src_l[64];
    __shared__ int dst_l[64];
    __shared__ float we1_l[32], be1_l[32];
    __shared__ float part_l[256];

    const int tid  = threadIdx.x;
    const int w    = tid >> 6;        // wave 0..3
    const int lane = tid & 63;
    const int l15  = lane & 15;
    const int quad = lane >> 4;
    const int c4   = tid & 15, sub = tid >> 4;

    float* outh = out;
    float* outx = out + NH;

    if (tid < 32) { we1_l[tid] = We1[tid]; be1_l[tid] = be1[tid]; }

    // ---- prologue: commutative init — out(=0) += h, x.  No sync needed:
    //      these atomicAdds commute with all message atomicAdds. ----
    {
        const int gtid = blockIdx.x * 256 + tid;
        const int G = GRID * 256;
        const float4* h4 = (const float4*)h;
#pragma unroll 1
        for (int i = gtid; i < NH / 4; i += G) {
            const float4 v = h4[i];
            atomicAdd(outh + i * 4 + 0, v.x);
            atomicAdd(outh + i * 4 + 1, v.y);
            atomicAdd(outh + i * 4 + 2, v.z);
            atomicAdd(outh + i * 4 + 3, v.w);
        }
#pragma unroll 1
        for (int i = gtid; i < NX; i += G) atomicAdd(outx + i, x[i]);
    }

    // ---- one-time: B-fragments with INLINE We2/be2 fold ----
    // W'[128+m, n] = sum_j We2[m*32+j] * W1[(128+j)*HDIM + n]  (= v4/v8 prep)
    bf16x8 wn1f[5][2], wc1f[5][2];
#pragma unroll
    for (int kc = 0; kc < 5; ++kc) {
#pragma unroll
        for (int nt = 0; nt < 2; ++nt) {
            unsigned short un[8], uc[8];
            const int n = w * 32 + nt * 16 + l15;
#pragma unroll
            for (int j = 0; j < 8; ++j) {
                const int k = kc * 32 + quad * 8 + j;
                float vn, vc;
                if (k < 128) {
                    vn = Wn1[k * HDIM + n];
                    vc = Wc1[k * HDIM + n];
                } else {
                    const int m = k - 128;      // s-slot index
                    vn = 0.0f; vc = 0.0f;
#pragma unroll
                    for (int jj = 0; jj < 32; ++jj) {
                        const float w2 = We2[m * 32 + jj];
                        vn += w2 * Wn1[(128 + jj) * HDIM + n];
                        vc += w2 * Wc1[(128 + jj) * HDIM + n];
                    }
                }
                un[j] = f2bf(vn); uc[j] = f2bf(vc);
            }
            wn1f[kc][nt] = mk_frag(un);
            wc1f[kc][nt] = mk_frag(uc);
        }
    }
    // GEMM2 B-frags, pi-permuted k (matches packed hl):
    // D(k) = (k&~31) + ((k&1)<<4) + ((k&31)>>1)
    bf16x8 wn2f[4];
#pragma unroll
    for (int kc = 0; kc < 4; ++kc) {
        unsigned short u[8];
        const int n = w * 16 + l15;
#pragma unroll
        for (int j = 0; j < 8; ++j) {
            const int k = kc * 32 + quad * 8 + j;
            const int D = (k & ~31) + ((k & 1) << 4) + ((k & 31) >> 1);
            u[j] = f2bf(Wn2[D * NDIM + n]);
        }
        wn2f[kc] = mk_frag(u);
    }
    // folded biases: bn1' = bn1 + be2 @ W1[128:160]
    float biasN0, biasN1, biasC0, biasC1;
    {
        const int n0 = w * 32 + l15, n1 = n0 + 16;
        float a0 = bn1[n0], a1 = bn1[n1], b0 = bc1[n0], b1 = bc1[n1];
#pragma unroll
        for (int m = 0; m < 32; ++m) {
            const float bm = be2[m];
            a0 += bm * Wn1[(128 + m) * HDIM + n0];
            a1 += bm * Wn1[(128 + m) * HDIM + n1];
            b0 += bm * Wc1[(128 + m) * HDIM + n0];
            b1 += bm * Wc1[(128 + m) * HDIM + n1];
        }
        biasN0 = a0; biasN1 = a1; biasC0 = b0; biasC1 = b1;
    }
    const float bias2v = bn2[w * 16 + l15];
    const float wcA = Wc2[w * 32 + l15];
    const float wcB = Wc2[w * 32 + 16 + l15];

    // ---- prologue prefetch: first tile's indices + dist ----
    int psn[4], pdn[4];
    float pdist;
    int psl = 0, pdl = 0;
    {
        const int e0 = blockIdx.x * 64;
#pragma unroll
        for (int it = 0; it < 4; ++it) {
            psn[it] = srcg[e0 + sub + it * 16];
            pdn[it] = dstg[e0 + sub + it * 16];
        }
        pdist = dist[e0 + (tid >> 2)];
        if (tid < 64) { psl = srcg[e0 + tid]; pdl = dstg[e0 + tid]; }
    }

    for (int tile = blockIdx.x; tile < NTILES; tile += gridDim.x) {
        bar_lds();   // (1) previous tile's LDS reads all done

        // ---- stage m_input = [h[src] | h[dst] | s]; x epilogue loads ----
        float xs0 = 0, xs1 = 0, xs2 = 0, xd0 = 0, xd1 = 0, xd2 = 0;
        if (tid < 64) {
            src_l[tid] = psl; dst_l[tid] = pdl;
            xs0 = x[psl * 3 + 0]; xs1 = x[psl * 3 + 1]; xs2 = x[psl * 3 + 2];
            xd0 = x[pdl * 3 + 0]; xd1 = x[pdl * 3 + 1]; xd2 = x[pdl * 3 + 2];
        }
#pragma unroll
        for (int it = 0; it < 4; ++it) {
            const int el = sub + it * 16;
            const float4 hs = *(const float4*)(h + (size_t)psn[it] * NDIM + c4 * 4);
            const float4 hd = *(const float4*)(h + (size_t)pdn[it] * NDIM + c4 * 4);
            ushort4v us = { f2bf(hs.x), f2bf(hs.y), f2bf(hs.z), f2bf(hs.w) };
            ushort4v ud = { f2bf(hd.x), f2bf(hd.y), f2bf(hd.z), f2bf(hd.w) };
            *(ushort4v*)&mlds[el * MSTRIDE + c4 * 4] = us;
            *(ushort4v*)&mlds[el * MSTRIDE + 64 + c4 * 4] = ud;
        }
        {
            const int el = tid >> 2, j0 = (tid & 3) * 8;
            ushort8 u;
#pragma unroll
            for (int j = 0; j < 8; ++j)
                u[j] = f2bf(silu(pdist * we1_l[j0 + j] + be1_l[j0 + j]));
            *(ushort8*)&mlds[el * MSTRIDE + 128 + j0] = u;
        }
        bar_lds();   // (2) m_input ready

        // ---- prefetch next tile's indices (lands under GEMM1) ----
        {
            const int tn = tile + (int)gridDim.x;
            const int eb = (tn < NTILES ? tn : tile) * 64;
#pragma unroll
            for (int it = 0; it < 4; ++it) {
                psn[it] = srcg[eb + sub + it * 16];
                pdn[it] = dstg[eb + sub + it * 16];
            }
            pdist = dist[eb + (tid >> 2)];
            if (tid < 64) { psl = srcg[eb + tid]; pdl = dstg[eb + tid]; }
        }

        // ---- GEMM1 merged: [64x160] @ {Wn1', Wc1'} ----
        f32x4 accN[4][2], accC[4][2];
#pragma unroll
        for (int mt = 0; mt < 4; ++mt) {
            accN[mt][0] = (f32x4){biasN0, biasN0, biasN0, biasN0};
            accN[mt][1] = (f32x4){biasN1, biasN1, biasN1, biasN1};
            accC[mt][0] = (f32x4){biasC0, biasC0, biasC0, biasC0};
            accC[mt][1] = (f32x4){biasC1, biasC1, biasC1, biasC1};
        }
#pragma unroll
        for (int kc = 0; kc < 5; ++kc) {
            bf16x8 af[4];
#pragma unroll
            for (int mt = 0; mt < 4; ++mt)
                af[mt] = ld_frag(&mlds[(mt * 16 + l15) * MSTRIDE + kc * 32 + quad * 8]);
#pragma unroll
            for (int mt = 0; mt < 4; ++mt) {
#pragma unroll
                for (int nt = 0; nt < 2; ++nt) {
                    accN[mt][nt] = __builtin_amdgcn_mfma_f32_16x16x32_bf16(
                        af[mt], wn1f[kc][nt], accN[mt][nt], 0, 0, 0);
                    accC[mt][nt] = __builtin_amdgcn_mfma_f32_16x16x32_bf16(
                        af[mt], wc1f[kc][nt], accC[mt][nt], 0, 0, 0);
                }
            }
        }

        // ---- node path: silu -> hl, packed b32 writes (pi-permuted cols) ----
        {
            unsigned int* hlu = (unsigned int*)hl;
#pragma unroll
            for (int mt = 0; mt < 4; ++mt)
#pragma unroll
                for (int r = 0; r < 4; ++r) {
                    const unsigned int u0 = f2bf(silu(accN[mt][0][r]));
                    const unsigned int u1 = f2bf(silu(accN[mt][1][r]));
                    hlu[(mt * 16 + quad * 4 + r) * (HSTRIDE / 2) + w * 16 + l15] =
                        (u1 << 16) | u0;
                }
        }

        // ---- coord path: in-register silu*Wc2 + butterfly reduce over l15 ----
        {
            float p[16];
#pragma unroll
            for (int mt = 0; mt < 4; ++mt)
#pragma unroll
                for (int r = 0; r < 4; ++r)
                    p[mt * 4 + r] = silu(accC[mt][0][r]) * wcA + silu(accC[mt][1][r]) * wcB;

            float q8[8];
#pragma unroll
            for (int i = 0; i < 8; ++i) {
                const float send = (l15 & 8) ? p[i] : p[i + 8];
                const float recv = __shfl_xor(send, 8, 64);
                q8[i] = ((l15 & 8) ? p[i + 8] : p[i]) + recv;
            }
            float q4[4];
#pragma unroll
            for (int i = 0; i < 4; ++i) {
                const float send = (l15 & 4) ? q8[i] : q8[i + 4];
                const float recv = __shfl_xor(send, 4, 64);
                q4[i] = ((l15 & 4) ? q8[i + 4] : q8[i]) + recv;
            }
            float q2[2];
#pragma unroll
            for (int i = 0; i < 2; ++i) {
                const float send = (l15 & 2) ? q4[i] : q4[i + 2];
                const float recv = __shfl_xor(send, 2, 64);
                q2[i] = ((l15 & 2) ? q4[i + 2] : q4[i]) + recv;
            }
            {
                const float send = (l15 & 1) ? q2[0] : q2[1];
                const float recv = __shfl_xor(send, 1, 64);
                const float tot = ((l15 & 1) ? q2[1] : q2[0]) + recv;
                const int edge = (l15 >> 2) * 16 + quad * 4 + (l15 & 3);
                part_l[w * 64 + edge] = tot;
            }
        }
        bar_lds();   // (3) hl + part_l ready

        // ---- GEMM2: [64x128] @ Wn2(pi) -> m [64x64], direct atomic scatter ----
        {
            f32x4 acc2[4];
#pragma unroll
            for (int mt = 0; mt < 4; ++mt) acc2[mt] = (f32x4){bias2v, bias2v, bias2v, bias2v};
#pragma unroll
            for (int kc = 0; kc < 4; ++kc) {
#pragma unroll
                for (int mt = 0; mt < 4; ++mt) {
                    bf16x8 a2 = ld_frag(&hl[(mt * 16 + l15) * HSTRIDE + kc * 32 + quad * 8]);
                    acc2[mt] = __builtin_amdgcn_mfma_f32_16x16x32_bf16(a2, wn2f[kc], acc2[mt], 0, 0, 0);
                }
            }
#pragma unroll
            for (int mt = 0; mt < 4; ++mt) {
#pragma unroll
                for (int r = 0; r < 4; ++r) {
                    const int el = mt * 16 + quad * 4 + r;
                    atomicAdd(outh + (size_t)dst_l[el] * NDIM + w * 16 + l15, acc2[mt][r]);
                }
            }
        }

        // ---- coord epilogue from prefetched x regs ----
        if (tid < 64) {
            const float cw = part_l[tid] + part_l[64 + tid] + part_l[128 + tid] + part_l[192 + tid];
            const float dx = xs0 - xd0;
            const float dy = xs1 - xd1;
            const float dz = xs2 - xd2;
            float len = sqrtf(dx * dx + dy * dy + dz * dz);
            len = fmaxf(len, 1e-8f);
            const float f = cw / len;
            const int dn = dst_l[tid];
            atomicAdd(outx + (size_t)dn * 3 + 0, f * dx);
            atomicAdd(outx + (size_t)dn * 3 + 1, f * dy);
            atomicAdd(outx + (size_t)dn * 3 + 2, f * dz);
        }
    }
}

extern "C" void kernel_launch(void* const* d_in, const int* in_sizes, int n_in,
                              void* d_out, int out_size, void* d_ws, size_t ws_size,
                              hipStream_t stream) {
    const float* h    = (const float*)d_in[0];
    const float* x    = (const float*)d_in[1];
    const int*   ei   = (const int*)d_in[2];     // int32, [2, NE]
    const float* dist = (const float*)d_in[3];
    const float* We1  = (const float*)d_in[4];
    const float* be1  = (const float*)d_in[5];
    const float* We2  = (const float*)d_in[6];
    const float* be2  = (const float*)d_in[7];
    const float* Wn1  = (const float*)d_in[8];
    const float* bn1  = (const float*)d_in[9];
    const float* Wn2  = (const float*)d_in[10];
    const float* bn2  = (const float*)d_in[11];
    const float* Wc1  = (const float*)d_in[12];
    const float* bc1  = (const float*)d_in[13];
    const float* Wc2  = (const float*)d_in[14];

    // zero out; h/x are atomically added inside the kernel (commutative with
    // the message scatters -> single launch, no grid sync).
    hipMemsetAsync(d_out, 0, (size_t)(NH + NX) * 4, stream);
    egnn_all<<<GRID, 256, 0, stream>>>(h, x, ei, ei + NE, dist,
                                       We1, be1, We2, be2,
                                       Wn1, bn1, Wn2, bn2,
                                       Wc1, bc1, Wc2,
                                       (float*)d_out);
}